// Round 2
// 818.628 us; speedup vs baseline: 1.1738x; 1.1738x over previous
//
#include <hip/hip_runtime.h>

// RNNBlock: h_t = relu(x_t @ W + h_{t-1} @ U + b) over reversed T, then
// out = relu(h @ W1 + b1).  B=65536, T=79, F=8, C=DW=256.
//
// R7 = R5 + XOR-decomposed immediate-folded LDS addressing.
// R5 counter evidence: step time ~6720 cyc/CU ~= serial sum of MFMA(2.2k) +
// DS(2.0k) + VALU(1.8k) + overhead; VALU dominated by per-step recompute of
// swizzled LDS addresses (runtime buf toggle + non-separable indexing).
// R7 keeps R5's MEASURED conflict-free layout (SQ_LDS_BANK_CONFLICT=0):
//   byte(r,c) = (r&63)*512 + (((c>>3) ^ (r&31))<<4) + (c&7)*2
// and exploits that row/granule/byte fields are disjoint bits, so:
//   read  addr = rbase ^ (kf<<5),  rbase = (l31<<9)^(q<<4)^(l31<<4)
//                mf -> +16384 imm, buf -> +32768 imm (ds offset field)
//   write addr = wbase ^ Kg,       wbase = (q<<11)^(q<<6)^((n>>3)<<4)^((n&7)<<1)
//                Kg = (rr_g<<9)|(rr_g<<4) compile-time, acc1 -> +16384 imm
// => per-step LDS addressing = 1 v_xor_b32 (literal) per access, no other VALU.
// Compile-time buffer parity via peeled s=0 + T-loop unrolled by 2.
// Barrier moved BEFORE the x f32->f16 convert so x-load latency hides under
// the barrier wait; the 2 init MFMAs sit between barrier and ds_reads.
//
// SPLIT LAW (R2/R3/R4): with MFMA builtins at waves_per_eu(2,2) the per-wave
// unified budget 256 splits V=128/A=128; exceeding V=128 goes to SCRATCH not
// AGPR (R4: 2.6 GB scratch). Budget here: bf 68 + bases 2 + xoff 2 + temps
// (~16 x-regs live across barrier, ~8 xa, ~8-16 ds dests) ~= 110-120 <= 128.
// acc0/acc1 (32 regs) are MFMA-only -> AGPRs.  WATCH VGPR_Count.
//
// Bank check (per 8-lane phase of wave64 b128 read, 128 B = 32 banks):
// granule = 2kf ^ q ^ l31 -> 8 consecutive-block granules per phase = 32
// distinct banks, conflict-free (matches R5 measured 0). Writes: 16 banks x
// 2-way (q=0) + other 16 banks x 2-way (q=1) = free (m136: 2-way free).
//
// MFMA v_mfma_f32_32x32x16_f16 layouts (learn_hip verified):
//   A[m][k]: m = lane&31, k = 8*(lane>>5) + j
//   B[k][n]: k = 8*(lane>>5) + j, n = lane&31
//   C/D    : col = lane&31, row = (reg&3) + 8*(reg>>2) + 4*(lane>>5)

#define B_ROWS 65536
#define T_STEPS 79
#define F_IN 8
#define C_DIM 256

typedef _Float16 h16;
typedef __attribute__((ext_vector_type(8))) _Float16 half8;
typedef __attribute__((ext_vector_type(16))) float f32x16;
typedef __attribute__((ext_vector_type(4))) float f32x4;

// B-fragments for the 272x256 augmented weight, this wave's column n.
// rows 0..255 = M (U or W1), 256..263 = Wx (or 0), 264 = bias, 265..271 = 0.
__device__ __forceinline__ void load_bfrags(half8 bf[17],
                                            const float* __restrict__ M,
                                            const float* __restrict__ Wx,
                                            const float* __restrict__ bias,
                                            int n, int q) {
  #pragma unroll
  for (int kf = 0; kf < 16; ++kf) {
    const int k0 = 16 * kf + 8 * q;
    half8 v;
    #pragma unroll
    for (int j = 0; j < 8; ++j)
      v[j] = (h16)M[(size_t)(k0 + j) * C_DIM + n];
    bf[kf] = v;
  }
  half8 v;
  #pragma unroll
  for (int j = 0; j < 8; ++j) v[j] = (h16)0.f;
  if (q == 0) {
    if (Wx) {
      #pragma unroll
      for (int j = 0; j < 8; ++j) v[j] = (h16)Wx[j * C_DIM + n];
    }
  } else {
    v[0] = (h16)bias[n];  // k=264 pairs with A-side constant 1.0
  }
  bf[16] = v;
}

// ---- per-step building blocks (macros so all LDS offsets are immediates) ---

// issue global x loads (q==0 lanes), advance to previous t
#define LOAD_X(lo, hi)                                                      \
  f32x4 lo[2], hi[2];                                                       \
  if (q == 0) {                                                             \
    _Pragma("unroll") for (int mf = 0; mf < 2; ++mf) {                      \
      const f32x4* xp = (const f32x4*)(xbase + xoff[mf]);                   \
      lo[mf] = xp[0];                                                       \
      hi[mf] = xp[1];                                                       \
      xoff[mf] -= F_IN * 4;                                                 \
    }                                                                       \
  }

#define MAKE_XA(xa, lo, hi)                                                 \
  half8 xa[2];                                                              \
  _Pragma("unroll") for (int mf = 0; mf < 2; ++mf) {                        \
    if (q == 0) {                                                           \
      half8 v;                                                              \
      v[0] = (h16)lo[mf][0]; v[1] = (h16)lo[mf][1];                         \
      v[2] = (h16)lo[mf][2]; v[3] = (h16)lo[mf][3];                         \
      v[4] = (h16)hi[mf][0]; v[5] = (h16)hi[mf][1];                         \
      v[6] = (h16)hi[mf][2]; v[7] = (h16)hi[mf][3];                         \
      xa[mf] = v;                                                           \
    } else {                                                                \
      half8 v;                                                              \
      _Pragma("unroll") for (int j = 0; j < 8; ++j) v[j] = (h16)0.f;        \
      v[0] = (h16)1.f; /* bias partner; remat-cheap movs */                 \
      xa[mf] = v;                                                           \
    }                                                                       \
  }

// write h (relu, fp16) into buffer WB; wbase ^ const + offset immediates
#define EPILOGUE(acc0, acc1, WB)                                            \
  _Pragma("unroll") for (int g = 0; g < 16; ++g) {                          \
    const int rr_g = (g & 3) + ((g >> 2) << 3);                             \
    const int Kg = (rr_g << 9) | (rr_g << 4);                               \
    char* const wp = lds + (wbase ^ Kg);                                    \
    *(h16*)(wp + (WB) * 32768) = (h16)fmaxf(acc0[g], 0.f);                  \
    *(h16*)(wp + (WB) * 32768 + 16384) = (h16)fmaxf(acc1[g], 0.f);          \
  }

#define STEP(RBUF)                                                          \
  do {                                                                      \
    LOAD_X(lo_, hi_);                                                       \
    __syncthreads(); /* h(s-1) writes visible; hides x-load latency */      \
    MAKE_XA(xa_, lo_, hi_);                                                 \
    f32x16 acc0_ = __builtin_amdgcn_mfma_f32_32x32x16_f16(                  \
        xa_[0], bf[16], (f32x16)(0.f), 0, 0, 0);                            \
    f32x16 acc1_ = __builtin_amdgcn_mfma_f32_32x32x16_f16(                  \
        xa_[1], bf[16], (f32x16)(0.f), 0, 0, 0);                            \
    _Pragma("unroll") for (int kf = 0; kf < 16; ++kf) {                     \
      const char* const rp = lds + (rbase ^ (kf << 5));                     \
      const half8 a0_ = *(const half8*)(rp + (RBUF)*32768);                 \
      acc0_ = __builtin_amdgcn_mfma_f32_32x32x16_f16(a0_, bf[kf], acc0_,    \
                                                     0, 0, 0);              \
      const half8 a1_ = *(const half8*)(rp + (RBUF)*32768 + 16384);         \
      acc1_ = __builtin_amdgcn_mfma_f32_32x32x16_f16(a1_, bf[kf], acc1_,    \
                                                     0, 0, 0);              \
    }                                                                       \
    EPILOGUE(acc0_, acc1_, (RBUF) ^ 1);                                     \
  } while (0)

__global__ __launch_bounds__(512)
__attribute__((amdgpu_waves_per_eu(2, 2)))
void rnn_fused(const float* __restrict__ x, const float* __restrict__ W,
               const float* __restrict__ U, const float* __restrict__ b,
               const float* __restrict__ W1, const float* __restrict__ b1,
               float* __restrict__ out) {
  __shared__ alignas(16) h16 hbuf[2][64 * 256];  // 2 x 32 KB

  const int tid = threadIdx.x;
  const int lane = tid & 63;
  const int wave = tid >> 6;        // 0..7, owns cols [32w, 32w+32)
  const int l31 = lane & 31;
  const int q = lane >> 5;
  const int row0 = blockIdx.x << 6; // 64 batch rows per block
  const int n = (wave << 5) + l31;  // this lane's output column

  half8 bf[17];
  load_bfrags(bf, U, W, b, n, q);

  char* const lds = (char*)hbuf;

  // XOR-separable base addresses (see header comment for derivation)
  const int rbase = (l31 << 9) ^ (q << 4) ^ (l31 << 4);
  const int wbase = (q << 11) ^ (q << 6) ^ ((n >> 3) << 4) ^ ((n & 7) << 1);

  const char* const xbase = (const char*)x;
  int xoff[2];
  #pragma unroll
  for (int mf = 0; mf < 2; ++mf)
    xoff[mf] = ((row0 + (mf << 5) + l31) * (T_STEPS * F_IN) +
                (T_STEPS - 1) * F_IN)
               << 2;

  // ---- s = 0 (t = 78): h0 = 0, no LDS read, writes buf1, no barrier ----
  {
    LOAD_X(lo_, hi_);
    MAKE_XA(xa_, lo_, hi_);
    f32x16 acc0_ = __builtin_amdgcn_mfma_f32_32x32x16_f16(
        xa_[0], bf[16], (f32x16)(0.f), 0, 0, 0);
    f32x16 acc1_ = __builtin_amdgcn_mfma_f32_32x32x16_f16(
        xa_[1], bf[16], (f32x16)(0.f), 0, 0, 0);
    EPILOGUE(acc0_, acc1_, 1);
  }

  // ---- s = 1..78 as 39 unrolled pairs: odd s reads buf1, even s buf0 ----
  #pragma unroll 1
  for (int sp = 0; sp < (T_STEPS - 1) / 2; ++sp) {
    STEP(1);
    STEP(0);
  }
  // last step (s=78, even) read buf0 and wrote h(final) into buf1

  // ---- final Dense(256, relu): same GEMM with W1/b1, x rows zeroed ----
  load_bfrags(bf, W1, nullptr, b1, n, q);
  half8 xaf;
  #pragma unroll
  for (int j = 0; j < 8; ++j) xaf[j] = (h16)0.f;
  if (q == 1) xaf[0] = (h16)1.f;

  f32x16 acc0 = __builtin_amdgcn_mfma_f32_32x32x16_f16(
      xaf, bf[16], (f32x16)(0.f), 0, 0, 0);
  f32x16 acc1 = __builtin_amdgcn_mfma_f32_32x32x16_f16(
      xaf, bf[16], (f32x16)(0.f), 0, 0, 0);

  __syncthreads();  // h(final) writes visible in buf1

  #pragma unroll
  for (int kf = 0; kf < 16; ++kf) {
    const char* const rp = lds + (rbase ^ (kf << 5));
    const half8 a0 = *(const half8*)(rp + 32768);
    acc0 = __builtin_amdgcn_mfma_f32_32x32x16_f16(a0, bf[kf], acc0, 0, 0, 0);
    const half8 a1 = *(const half8*)(rp + 32768 + 16384);
    acc1 = __builtin_amdgcn_mfma_f32_32x32x16_f16(a1, bf[kf], acc1, 0, 0, 0);
  }

  #pragma unroll
  for (int g = 0; g < 16; ++g) {
    const int rr = (g & 3) + ((g >> 2) << 3) + (q << 2);
    out[(size_t)(row0 + rr) * C_DIM + n] = fmaxf(acc0[g], 0.f);
    out[(size_t)(row0 + 32 + rr) * C_DIM + n] = fmaxf(acc1[g], 0.f);
  }
}

extern "C" void kernel_launch(void* const* d_in, const int* in_sizes, int n_in,
                              void* d_out, int out_size, void* d_ws,
                              size_t ws_size, hipStream_t stream) {
  const float* x  = (const float*)d_in[0];
  const float* W  = (const float*)d_in[1];
  const float* U  = (const float*)d_in[2];
  const float* b  = (const float*)d_in[3];
  const float* W1 = (const float*)d_in[4];
  const float* b1 = (const float*)d_in[5];
  float* out = (float*)d_out;

  rnn_fused<<<B_ROWS / 64, 512, 0, stream>>>(x, W, U, b, W1, b1, out);
}